// Round 14
// baseline (247.182 us; speedup 1.0000x reference)
//
#include <hip/hip_runtime.h>
#include <hip/hip_fp8.h>

// ---------------------------------------------------------------------------
// TripletContrastiveLoss on MI355X (gfx950)  — Round 14
// Base: R12 tile shape (dbuf async, 64-B rows, 1 barrier/step — best measured,
// 93 µs) + R13 launcher (5 nodes, verified -11 µs). ONE variable: features
// staged as fp8 e4m3 instead of bf16. Same byte-geometry per K-step but BK=64
// -> 16 steps (half the barriers), 256 MB staged (half), same MFMA count
// (non-scaled fp8 = bf16 rate). Numerics: dot err ~1e-3 << 6.7e-3 threshold;
// sqG from fp8-dequantized values keeps d^2 self-consistent.
// R13 lesson kept: no 128-B-row LDS (bank conflicts), no single-buffer.
// ---------------------------------------------------------------------------

#define B_ROWS 8192
#define DIM    1024

typedef float f32x4 __attribute__((ext_vector_type(4)));

// Async global->LDS, 16 B per lane; LDS dest wave-uniform, lane i at base+16i.
__device__ __forceinline__ void async_copy16(const void* g, void* l) {
    __builtin_amdgcn_global_load_lds(
        (const __attribute__((address_space(1))) unsigned int*)g,
        (__attribute__((address_space(3))) unsigned int*)l,
        16, 0, 0);
}

// ---------------------------------------------------------------------------
// Kernel 0: slot assignment via LDS prefix scan. 1 block x 256 threads,
// 32 rows/thread. Zero atomics. slotOf overlays posmin (consumed by
// normalize_rows, then clobbered by the 0xFF memset — stream-ordered).
// Writes cnt[0] = nA unconditionally (no cnt memset needed).
// ---------------------------------------------------------------------------
__global__ __launch_bounds__(256) void compute_slots(
    const int* __restrict__ dom, int* __restrict__ slotOf,
    unsigned* __restrict__ cnt)
{
    __shared__ int cnts[256];
    __shared__ int base[257];
    const int t = threadIdx.x;
    const int p0 = t * 32;

    unsigned mask = 0u; int c = 0;
    #pragma unroll
    for (int i = 0; i < 32; ++i) {
        const int isA = (dom[p0 + i] == 0) ? 1 : 0;
        mask |= ((unsigned)isA) << i;
        c += isA;
    }
    cnts[t] = c;
    __syncthreads();
    if (t == 0) {
        int acc = 0;
        for (int i = 0; i < 256; ++i) { base[i] = acc; acc += cnts[i]; }
        base[256] = acc;
        cnt[0] = (unsigned)acc;                  // nA
    }
    __syncthreads();
    const int nA = base[256];
    int aB = base[t];
    #pragma unroll
    for (int i = 0; i < 32; ++i) {
        const int isA = (mask >> i) & 1;
        slotOf[p0 + i] = isA ? aB : nA + (p0 + i - aB);
        aB += isA;
    }
}

// ---------------------------------------------------------------------------
// Kernel 1: one row per WAVE (2048 blocks x 4 waves). L2-normalize fp32,
// quantize to fp8 e4m3 (RNE via HW cvt), scatter to slotOf[row].
// sqG[slot] = sum of squares of the fp8-DEQUANTIZED row (self-consistent
// with the fp8 MFMA dot products). 4-byte packed stores, coalesced.
// ---------------------------------------------------------------------------
__global__ __launch_bounds__(256) void normalize_rows(
    const float* __restrict__ feat, const int* __restrict__ labels,
    const int* __restrict__ slotOf, unsigned char* __restrict__ G,
    int* __restrict__ labG, float* __restrict__ sqG)
{
    const int wv = threadIdx.x >> 6, lane = threadIdx.x & 63;
    const int row = blockIdx.x * 4 + wv;

    const float4* src = (const float4*)(feat + (size_t)row * DIM);
    float4 v[4];
    float ss = 0.0f;
    #pragma unroll
    for (int j = 0; j < 4; ++j) {
        v[j] = src[j * 64 + lane];
        ss += v[j].x * v[j].x + v[j].y * v[j].y + v[j].z * v[j].z + v[j].w * v[j].w;
    }
    #pragma unroll
    for (int s = 32; s > 0; s >>= 1) ss += __shfl_xor(ss, s);
    const float inv = 1.0f / fmaxf(sqrtf(ss), 1e-12f);

    const int slot = slotOf[row];
    unsigned pk[4];
    float ss2 = 0.0f;
    #pragma unroll
    for (int j = 0; j < 4; ++j) {
        const float f[4] = {v[j].x * inv, v[j].y * inv, v[j].z * inv, v[j].w * inv};
        union { unsigned u; unsigned char b[4]; } p;
        #pragma unroll
        for (int q = 0; q < 4; ++q) {
            __hip_fp8_e4m3 h(f[q]);
            p.b[q] = h.__x;
            const float fr = (float)h;
            ss2 += fr * fr;
        }
        pk[j] = p.u;
    }
    #pragma unroll
    for (int s = 32; s > 0; s >>= 1) ss2 += __shfl_xor(ss2, s);
    if (lane == 0) {
        sqG[slot]  = ss2;
        labG[slot] = labels[row];
    }
    unsigned* dst = (unsigned*)(G + (size_t)slot * DIM);
    #pragma unroll
    for (int j = 0; j < 4; ++j) dst[j * 64 + lane] = pk[j];
}

// ---------------------------------------------------------------------------
// Kernel 2: persistent 128x128 tiles, 4 waves (each 64x64 via 4x4 grid of
// 16x16x32 fp8_fp8 MFMA). K=1024 in 16 steps of BK=64 (= 64 B/row/step, same
// byte-geometry as the proven R12 step). Staging via global_load_lds
// width=16 (chunk = 16 rows x 64 B; 4 async/wave/step), double-buffered
// unpadded LDS (2x2x8 KB = 32 KB), ONE barrier per step.
// A/B fragment: lane(l15,quad) -> row l15, k = quad*8 + j (8 consecutive
// bytes, read as long). C/D layout dtype-independent (verified claim).
// Epilogue: min d^2 per anchor row -> atomicMin (uint order, d^2 >= 0).
// ---------------------------------------------------------------------------
__global__ __launch_bounds__(256) void tile_mindist(
    const unsigned char* __restrict__ G, const int* __restrict__ labG,
    const float* __restrict__ sqG, const unsigned* __restrict__ cnt,
    unsigned* __restrict__ posmin, unsigned* __restrict__ negmin)
{
    const int nA = (int)cnt[0];
    const int nF = B_ROWS - nA;
    const int nTA = (nA + 127) >> 7;
    const int nTF = (nF + 127) >> 7;
    const int total = nTA * nTF;

    // [buf][A=0/F=1][128 rows x 64 B] = 32,768 B
    __shared__ __align__(16) unsigned char S[2][2][128 * 64];

    const int t = threadIdx.x;
    const int lane = t & 63, w = t >> 6;
    const int wm = w >> 1, wn = w & 1;          // wave sub-tile coords (x64)
    const int l15 = lane & 15, quad = lane >> 4;

    // Async staging: chunk ch = rows [16ch,16ch+16) x 64 B; wave w owns
    // chunks 2w, 2w+1 of both arrays. Lane: row 16ch + (lane>>2),
    // byte col (lane&3)*16.
    const int ch0 = 2 * w;
    const int crow = lane >> 2;
    const int cbyte = (lane & 3) * 16;

    // Fragment read byte offsets, row stride 64 B.
    const int rdA = (wm * 64 + l15) * 64 + quad * 8;
    const int rdF = (wn * 64 + l15) * 64 + quad * 8;

    for (int tile = blockIdx.x; tile < total; tile += gridDim.x) {
        const int tx = tile % nTA;
        const int ty = tile / nTA;
        const int rowA0 = tx * 128;
        const int rowF0 = nA + ty * 128;

        const unsigned char* ga[2]; const unsigned char* gf[2];
        #pragma unroll
        for (int h = 0; h < 2; ++h) {
            const int ch = ch0 + h;
            const int rA = rowA0 + 16 * ch + crow;          // < 8192 always
            int rF = rowF0 + 16 * ch + crow;
            if (rF > B_ROWS - 1) rF = B_ROWS - 1;           // clamp; masked later
            ga[h] = G + (size_t)rA * DIM + cbyte;
            gf[h] = G + (size_t)rF * DIM + cbyte;
        }

        f32x4 acc[4][4] = {};

        // Prologue: stage K-chunk 0 into buffer 0.
        #pragma unroll
        for (int h = 0; h < 2; ++h) {
            async_copy16(ga[h], &S[0][0][(ch0 + h) * 1024]);
            async_copy16(gf[h], &S[0][1][(ch0 + h) * 1024]);
        }
        __syncthreads();                         // drains vmcnt (buf0 ready)

        #pragma unroll 4
        for (int step = 0; step < 16; ++step) {
            const int cur = step & 1;
            const int nb = cur ^ 1;
            if (step < 15) {                     // async-stage step+1 into nb
                const int off = (step + 1) * 64; // 64 B of K per step
                #pragma unroll
                for (int h = 0; h < 2; ++h) {
                    async_copy16(ga[h] + off, &S[nb][0][(ch0 + h) * 1024]);
                    async_copy16(gf[h] + off, &S[nb][1][(ch0 + h) * 1024]);
                }
            }

            long a[4][2], b[4][2];
            #pragma unroll
            for (int u = 0; u < 2; ++u) {        // two K=32 halves of BK=64
                #pragma unroll
                for (int fm = 0; fm < 4; ++fm)
                    a[fm][u] = *(const long*)(&S[cur][0][rdA + fm * 1024 + u * 32]);
                #pragma unroll
                for (int fn = 0; fn < 4; ++fn)
                    b[fn][u] = *(const long*)(&S[cur][1][rdF + fn * 1024 + u * 32]);
            }
            #pragma unroll
            for (int u = 0; u < 2; ++u)
                #pragma unroll
                for (int fm = 0; fm < 4; ++fm)
                    #pragma unroll
                    for (int fn = 0; fn < 4; ++fn)
                        acc[fm][fn] = __builtin_amdgcn_mfma_f32_16x16x32_fp8_fp8(
                            a[fm][u], b[fn][u], acc[fm][fn], 0, 0, 0);

            __syncthreads();   // one barrier: completes nb loads, frees cur
        }

        // Epilogue. C/D layout: col = lane&15 (field), row = quad*4+reg (anchor).
        const float INFV = __uint_as_float(0x7f800000u);
        float sqf[4]; int lf_[4]; bool vf[4];
        #pragma unroll
        for (int fn = 0; fn < 4; ++fn) {
            const int rf = rowF0 + wn * 64 + fn * 16 + l15;
            vf[fn] = rf < B_ROWS;
            const int rc = vf[fn] ? rf : (B_ROWS - 1);
            sqf[fn] = sqG[rc];
            lf_[fn] = labG[rc];
        }
        #pragma unroll
        for (int fm = 0; fm < 4; ++fm) {
            #pragma unroll
            for (int r = 0; r < 4; ++r) {
                const int ra = rowA0 + wm * 64 + fm * 16 + quad * 4 + r;
                const bool va = ra < nA;
                const int rac = va ? ra : 0;
                const float sqa = sqG[rac];
                const int la_ = labG[rac];
                float pmin = INFV, nmin = INFV;
                #pragma unroll
                for (int fn = 0; fn < 4; ++fn) {
                    const float dd = fmaxf(sqa + sqf[fn] - 2.0f * acc[fm][fn][r], 0.0f);
                    if (vf[fn]) {
                        if (la_ == lf_[fn]) pmin = fminf(pmin, dd);
                        else                nmin = fminf(nmin, dd);
                    }
                }
                #pragma unroll
                for (int s = 1; s < 16; s <<= 1) {
                    pmin = fminf(pmin, __shfl_xor(pmin, s));
                    nmin = fminf(nmin, __shfl_xor(nmin, s));
                }
                if (l15 == 0 && va) {
                    if (pmin < INFV) atomicMin(&posmin[ra], __float_as_uint(pmin));
                    if (nmin < INFV) atomicMin(&negmin[ra], __float_as_uint(nmin));
                }
            }
        }
        __syncthreads();   // protect LDS before next tile's prologue writes
    }
}

// ---------------------------------------------------------------------------
// Kernel 3: fused final reduce. 1 block x 256 threads, 32 independent load
// pairs per thread, wave+LDS reduce, write out[0]. Untouched slots stay
// 0xFFFFFFFF and drop out as invalid.
// ---------------------------------------------------------------------------
__global__ __launch_bounds__(256) void reduce_one(
    const unsigned* __restrict__ posmin, const unsigned* __restrict__ negmin,
    float* __restrict__ out)
{
    const int t = threadIdx.x;
    const int lane = t & 63, w = t >> 6;
    float tl = 0.0f, c = 0.0f;
    #pragma unroll
    for (int j = 0; j < 32; ++j) {
        const int i = j * 256 + t;
        const unsigned up = posmin[i], un = negmin[i];
        if (up != 0xFFFFFFFFu && un != 0xFFFFFFFFu) {
            const float pd = sqrtf(__uint_as_float(up));
            const float nd = sqrtf(__uint_as_float(un));
            tl += fmaxf(pd - nd + 0.3f, 0.0f);
            c += 1.0f;
        }
    }
    #pragma unroll
    for (int s = 32; s > 0; s >>= 1) {
        tl += __shfl_down(tl, s);
        c  += __shfl_down(c, s);
    }
    __shared__ float sb[8];
    if (lane == 0) { sb[w] = tl; sb[4 + w] = c; }
    __syncthreads();
    if (t == 0) {
        const float s = sb[0] + sb[1] + sb[2] + sb[3];
        const float cc = sb[4] + sb[5] + sb[6] + sb[7];
        out[0] = (cc > 0.0f) ? s / fmaxf(cc, 1.0f) : 0.0f;
    }
}

// ---------------------------------------------------------------------------
extern "C" void kernel_launch(void* const* d_in, const int* in_sizes, int n_in,
                              void* d_out, int out_size, void* d_ws, size_t ws_size,
                              hipStream_t stream) {
    const float* feat  = (const float*)d_in[0];
    const int* labels  = (const int*)d_in[1];
    const int* dom     = (const int*)d_in[2];
    float* out = (float*)d_out;

    char* ws = (char*)d_ws;
    // Workspace layout (bytes) — identical offsets to validated layout
    // (G region now uses 8 of its 16 MB):
    unsigned char* G    = (unsigned char*)(ws);                  // 8,388,608 used
    int*      labG      = (int*)(ws + 16777216);                 //     32,768
    float*    sqG       = (float*)(ws + 16809984);               //     32,768
    unsigned* posmin    = (unsigned*)(ws + 16842752);            //     32,768
    unsigned* negmin    = (unsigned*)(ws + 16875520);            //     32,768
    unsigned* cnt       = (unsigned*)(ws + 16908288);            //  8 (nA)
    // slotOf OVERLAYS posmin: written by compute_slots, consumed by
    // normalize_rows, then clobbered by the 0xFF memset (stream-ordered).
    int*      slotOf    = (int*)(ws + 16842752);

    compute_slots<<<1, 256, 0, stream>>>(dom, slotOf, cnt);
    normalize_rows<<<B_ROWS / 4, 256, 0, stream>>>(feat, labels, slotOf,
                                                   G, labG, sqG);

    hipMemsetAsync(posmin, 0xFF, 65536, stream);    // posmin+negmin = +inf bits

    // Max tiles over all nA splits: ceil(a/128)*ceil((8192-a)/128) <= 1056.
    tile_mindist<<<1056, 256, 0, stream>>>(G, labG, sqG, cnt, posmin, negmin);

    reduce_one<<<1, 256, 0, stream>>>(posmin, negmin, out);
}

// Round 15
// 182.920 us; speedup vs baseline: 1.3513x; 1.3513x over previous
//
#include <hip/hip_runtime.h>

// ---------------------------------------------------------------------------
// TripletContrastiveLoss on MI355X (gfx950)  — Round 15
// Base: R12 tile (bf16, dbuf async global_load_lds, 64-B rows, 1 barrier/step
// — best measured 93 µs) + R13 launcher (5 nodes, non-tile 76 µs).
// ONE variable: XCD-aware tile mapping. blockIdx&7 = XCD; each XCD owns a
// contiguous strip of ceil(nTF/8) F-tile rows (~1 MB F data -> resident in
// that XCD's 4 MB L2) and iterates all A-tiles within the strip. Kills the
// 8x cross-XCD L2 duplication of the linear mapping (R12/R14 analysis:
// tile is staging-bandwidth-bound at ~5.5 TB/s, 512 MB/dispatch).
// R14 lesson: fp8 reverted (b64 frag reads + VGPR growth regressed 1.6x).
// ---------------------------------------------------------------------------

#define B_ROWS 8192
#define DIM    1024

typedef __bf16 bf16x8 __attribute__((ext_vector_type(8)));
typedef float  f32x4  __attribute__((ext_vector_type(4)));

__device__ __forceinline__ unsigned short f2bf_rne(float x) {
    unsigned u = __float_as_uint(x);
    unsigned r = (u + 0x7FFFu + ((u >> 16) & 1u)) >> 16;
    return (unsigned short)r;
}
__device__ __forceinline__ float bf2f(unsigned short h) {
    return __uint_as_float(((unsigned)h) << 16);
}

// Async global->LDS, 16 B per lane; LDS dest wave-uniform, lane i at base+16i.
__device__ __forceinline__ void async_copy16(const void* g, void* l) {
    __builtin_amdgcn_global_load_lds(
        (const __attribute__((address_space(1))) unsigned int*)g,
        (__attribute__((address_space(3))) unsigned int*)l,
        16, 0, 0);
}

// ---------------------------------------------------------------------------
// Kernel 0: slot assignment via LDS prefix scan. 1 block x 256 threads,
// 32 rows/thread. Zero atomics. slotOf overlays posmin (consumed by
// normalize_rows, then clobbered by the 0xFF memset — stream-ordered).
// Writes cnt[0] = nA unconditionally (no cnt memset needed).
// ---------------------------------------------------------------------------
__global__ __launch_bounds__(256) void compute_slots(
    const int* __restrict__ dom, int* __restrict__ slotOf,
    unsigned* __restrict__ cnt)
{
    __shared__ int cnts[256];
    __shared__ int base[257];
    const int t = threadIdx.x;
    const int p0 = t * 32;

    unsigned mask = 0u; int c = 0;
    #pragma unroll
    for (int i = 0; i < 32; ++i) {
        const int isA = (dom[p0 + i] == 0) ? 1 : 0;
        mask |= ((unsigned)isA) << i;
        c += isA;
    }
    cnts[t] = c;
    __syncthreads();
    if (t == 0) {
        int acc = 0;
        for (int i = 0; i < 256; ++i) { base[i] = acc; acc += cnts[i]; }
        base[256] = acc;
        cnt[0] = (unsigned)acc;                  // nA
    }
    __syncthreads();
    const int nA = base[256];
    int aB = base[t];
    #pragma unroll
    for (int i = 0; i < 32; ++i) {
        const int isA = (mask >> i) & 1;
        slotOf[p0 + i] = isA ? aB : nA + (p0 + i - aB);
        aB += isA;
    }
}

// ---------------------------------------------------------------------------
// Kernel 1: one row per WAVE. 2048 blocks x 256 threads (4 waves). Wave-local
// shuffle reductions only. L2-normalize fp32, round to bf16, scatter to slot.
// sqG[slot] = sum of squares of the bf16-ROUNDED row.
// ---------------------------------------------------------------------------
__global__ __launch_bounds__(256) void normalize_rows(
    const float* __restrict__ feat, const int* __restrict__ labels,
    const int* __restrict__ slotOf, unsigned short* __restrict__ G,
    int* __restrict__ labG, float* __restrict__ sqG)
{
    const int wv = threadIdx.x >> 6, lane = threadIdx.x & 63;
    const int row = blockIdx.x * 4 + wv;

    const float4* src = (const float4*)(feat + (size_t)row * DIM);
    float4 v[4];
    float ss = 0.0f;
    #pragma unroll
    for (int j = 0; j < 4; ++j) {
        v[j] = src[j * 64 + lane];
        ss += v[j].x * v[j].x + v[j].y * v[j].y + v[j].z * v[j].z + v[j].w * v[j].w;
    }
    #pragma unroll
    for (int s = 32; s > 0; s >>= 1) ss += __shfl_xor(ss, s);
    const float inv = 1.0f / fmaxf(sqrtf(ss), 1e-12f);

    const int slot = slotOf[row];
    unsigned short ub[16];
    float ss2 = 0.0f;
    #pragma unroll
    for (int j = 0; j < 4; ++j) {
        const float f0 = v[j].x * inv, f1 = v[j].y * inv,
                    f2 = v[j].z * inv, f3 = v[j].w * inv;
        ub[j * 4 + 0] = f2bf_rne(f0); ub[j * 4 + 1] = f2bf_rne(f1);
        ub[j * 4 + 2] = f2bf_rne(f2); ub[j * 4 + 3] = f2bf_rne(f3);
        #pragma unroll
        for (int q = 0; q < 4; ++q) {
            const float fr = bf2f(ub[j * 4 + q]);
            ss2 += fr * fr;
        }
    }
    #pragma unroll
    for (int s = 32; s > 0; s >>= 1) ss2 += __shfl_xor(ss2, s);
    if (lane == 0) {
        sqG[slot]  = ss2;
        labG[slot] = labels[row];
    }
    ushort4* dst = (ushort4*)(G + (size_t)slot * DIM);
    #pragma unroll
    for (int j = 0; j < 4; ++j) {
        ushort4 pk;
        pk.x = ub[j * 4 + 0]; pk.y = ub[j * 4 + 1];
        pk.z = ub[j * 4 + 2]; pk.w = ub[j * 4 + 3];
        dst[j * 64 + lane] = pk;
    }
}

// ---------------------------------------------------------------------------
// Kernel 2: persistent 128x128 tiles, 4 waves (each 64x64 via 4x4 of
// 16x16x32 bf16 MFMA), K=1024 in 32 steps of BK=32. Staging via
// global_load_lds width=16 (4 async/wave/step), double-buffered unpadded LDS
// (32 KB), ONE barrier per step — R12's measured-best K-loop, unchanged.
// NEW: XCD-aware tile map. Grid 1056 = 8 XCDs x 132 slots; XCD x owns F-tile
// rows [x*strip, x*strip+strip), strip = ceil(nTF/8) (~1 MB F data, L2-
// resident), iterating tiles (tx fast) within the strip.
// Epilogue: min d^2 per anchor row -> atomicMin (uint order, d^2 >= 0).
// ---------------------------------------------------------------------------
__global__ __launch_bounds__(256) void tile_mindist(
    const unsigned short* __restrict__ G, const int* __restrict__ labG,
    const float* __restrict__ sqG, const unsigned* __restrict__ cnt,
    unsigned* __restrict__ posmin, unsigned* __restrict__ negmin)
{
    const int nA = (int)cnt[0];
    const int nF = B_ROWS - nA;
    const int nTA = (nA + 127) >> 7;
    const int nTF = (nF + 127) >> 7;
    if (nTA == 0 || nTF == 0) return;

    // XCD-local strip mapping. Consecutive blockIdx round-robin across XCDs,
    // so blockIdx&7 groups blocks by XCD; each XCD's 132 slots cover
    // nTA x strip tiles (max 33*4 = 132 at the worst nA split).
    const int strip = (nTF + 7) >> 3;
    const int xcd  = blockIdx.x & 7;
    const int slot = blockIdx.x >> 3;            // 0..131
    const int tyBase = xcd * strip;
    const int nloc = nTA * strip;

    // [buf][A=0/F=1][128 rows x 32 shorts (64 B, unpadded)] = 32,768 B
    __shared__ __align__(16) unsigned short S[2][2][128 * 32];

    const int t = threadIdx.x;
    const int lane = t & 63, w = t >> 6;
    const int wm = w >> 1, wn = w & 1;          // wave sub-tile coords (x64)
    const int l15 = lane & 15, quad = lane >> 4;

    // Async staging: chunk ch = rows [16ch,16ch+16); wave w owns chunks
    // 2w, 2w+1 of both arrays. Lane: row 16ch + (lane>>2), byte (lane&3)*16.
    const int ch0 = 2 * w;
    const int crow = lane >> 2;
    const int cbyte = (lane & 3) * 16;

    // Fragment read offsets (shorts), row stride 32 shorts.
    const int rdA = (wm * 64 + l15) * 32 + quad * 8;
    const int rdF = (wn * 64 + l15) * 32 + quad * 8;

    const char* Gb = (const char*)G;

    for (int idx = slot; idx < nloc; idx += 132) {
        const int ty = tyBase + idx / nTA;
        if (ty >= nTF) break;                    // ty monotone in idx
        const int tx = idx % nTA;
        const int rowA0 = tx * 128;
        const int rowF0 = nA + ty * 128;

        const char* ga[2]; const char* gf[2];
        #pragma unroll
        for (int h = 0; h < 2; ++h) {
            const int ch = ch0 + h;
            const int rA = rowA0 + 16 * ch + crow;          // < 8192 always
            int rF = rowF0 + 16 * ch + crow;
            if (rF > B_ROWS - 1) rF = B_ROWS - 1;           // clamp; masked later
            ga[h] = Gb + (size_t)rA * (DIM * 2) + cbyte;
            gf[h] = Gb + (size_t)rF * (DIM * 2) + cbyte;
        }

        f32x4 acc[4][4] = {};

        // Prologue: stage K-chunk 0 into buffer 0.
        #pragma unroll
        for (int h = 0; h < 2; ++h) {
            async_copy16(ga[h], &S[0][0][(ch0 + h) * 512]);
            async_copy16(gf[h], &S[0][1][(ch0 + h) * 512]);
        }
        __syncthreads();                         // drains vmcnt (buf0 ready)

        #pragma unroll 4
        for (int step = 0; step < 32; ++step) {
            const int cur = step & 1;
            const int nb = cur ^ 1;
            if (step < 31) {                     // async-stage step+1 into nb
                const int off = (step + 1) * 64; // 64 B of K per step
                #pragma unroll
                for (int h = 0; h < 2; ++h) {
                    async_copy16(ga[h] + off, &S[nb][0][(ch0 + h) * 512]);
                    async_copy16(gf[h] + off, &S[nb][1][(ch0 + h) * 512]);
                }
            }

            const unsigned short* pa = &S[cur][0][rdA];
            const unsigned short* pf = &S[cur][1][rdF];
            bf16x8 a[4], b[4];
            #pragma unroll
            for (int fm = 0; fm < 4; ++fm) a[fm] = *(const bf16x8*)(pa + fm * 512);
            #pragma unroll
            for (int fn = 0; fn < 4; ++fn) b[fn] = *(const bf16x8*)(pf + fn * 512);
            #pragma unroll
            for (int fm = 0; fm < 4; ++fm)
                #pragma unroll
                for (int fn = 0; fn < 4; ++fn)
                    acc[fm][fn] = __builtin_amdgcn_mfma_f32_16x16x32_bf16(
                        a[fm], b[fn], acc[fm][fn], 0, 0, 0);

            __syncthreads();   // one barrier: completes nb loads, frees cur
        }

        // Epilogue. C/D layout: col = lane&15 (field), row = quad*4+reg (anchor).
        const float INFV = __uint_as_float(0x7f800000u);
        float sqf[4]; int lf_[4]; bool vf[4];
        #pragma unroll
        for (int fn = 0; fn < 4; ++fn) {
            const int rf = rowF0 + wn * 64 + fn * 16 + l15;
            vf[fn] = rf < B_ROWS;
            const int rc = vf[fn] ? rf : (B_ROWS - 1);
            sqf[fn] = sqG[rc];
            lf_[fn] = labG[rc];
        }
        #pragma unroll
        for (int fm = 0; fm < 4; ++fm) {
            #pragma unroll
            for (int r = 0; r < 4; ++r) {
                const int ra = rowA0 + wm * 64 + fm * 16 + quad * 4 + r;
                const bool va = ra < nA;
                const int rac = va ? ra : 0;
                const float sqa = sqG[rac];
                const int la_ = labG[rac];
                float pmin = INFV, nmin = INFV;
                #pragma unroll
                for (int fn = 0; fn < 4; ++fn) {
                    const float dd = fmaxf(sqa + sqf[fn] - 2.0f * acc[fm][fn][r], 0.0f);
                    if (vf[fn]) {
                        if (la_ == lf_[fn]) pmin = fminf(pmin, dd);
                        else                nmin = fminf(nmin, dd);
                    }
                }
                #pragma unroll
                for (int s = 1; s < 16; s <<= 1) {
                    pmin = fminf(pmin, __shfl_xor(pmin, s));
                    nmin = fminf(nmin, __shfl_xor(nmin, s));
                }
                if (l15 == 0 && va) {
                    if (pmin < INFV) atomicMin(&posmin[ra], __float_as_uint(pmin));
                    if (nmin < INFV) atomicMin(&negmin[ra], __float_as_uint(nmin));
                }
            }
        }
        __syncthreads();   // protect LDS before next tile's prologue writes
    }
}

// ---------------------------------------------------------------------------
// Kernel 3: fused final reduce. 1 block x 256 threads, 32 independent load
// pairs per thread, wave+LDS reduce, write out[0]. Untouched slots stay
// 0xFFFFFFFF and drop out as invalid.
// ---------------------------------------------------------------------------
__global__ __launch_bounds__(256) void reduce_one(
    const unsigned* __restrict__ posmin, const unsigned* __restrict__ negmin,
    float* __restrict__ out)
{
    const int t = threadIdx.x;
    const int lane = t & 63, w = t >> 6;
    float tl = 0.0f, c = 0.0f;
    #pragma unroll
    for (int j = 0; j < 32; ++j) {
        const int i = j * 256 + t;
        const unsigned up = posmin[i], un = negmin[i];
        if (up != 0xFFFFFFFFu && un != 0xFFFFFFFFu) {
            const float pd = sqrtf(__uint_as_float(up));
            const float nd = sqrtf(__uint_as_float(un));
            tl += fmaxf(pd - nd + 0.3f, 0.0f);
            c += 1.0f;
        }
    }
    #pragma unroll
    for (int s = 32; s > 0; s >>= 1) {
        tl += __shfl_down(tl, s);
        c  += __shfl_down(c, s);
    }
    __shared__ float sb[8];
    if (lane == 0) { sb[w] = tl; sb[4 + w] = c; }
    __syncthreads();
    if (t == 0) {
        const float s = sb[0] + sb[1] + sb[2] + sb[3];
        const float cc = sb[4] + sb[5] + sb[6] + sb[7];
        out[0] = (cc > 0.0f) ? s / fmaxf(cc, 1.0f) : 0.0f;
    }
}

// ---------------------------------------------------------------------------
extern "C" void kernel_launch(void* const* d_in, const int* in_sizes, int n_in,
                              void* d_out, int out_size, void* d_ws, size_t ws_size,
                              hipStream_t stream) {
    const float* feat  = (const float*)d_in[0];
    const int* labels  = (const int*)d_in[1];
    const int* dom     = (const int*)d_in[2];
    float* out = (float*)d_out;

    char* ws = (char*)d_ws;
    // Workspace layout (bytes) — identical footprint to validated layout:
    unsigned short* G   = (unsigned short*)(ws);                 // 16,777,216
    int*      labG      = (int*)(ws + 16777216);                 //     32,768
    float*    sqG       = (float*)(ws + 16809984);               //     32,768
    unsigned* posmin    = (unsigned*)(ws + 16842752);            //     32,768
    unsigned* negmin    = (unsigned*)(ws + 16875520);            //     32,768
    unsigned* cnt       = (unsigned*)(ws + 16908288);            //  8 (nA)
    // slotOf OVERLAYS posmin: written by compute_slots, consumed by
    // normalize_rows, then clobbered by the 0xFF memset (stream-ordered).
    int*      slotOf    = (int*)(ws + 16842752);

    compute_slots<<<1, 256, 0, stream>>>(dom, slotOf, cnt);
    normalize_rows<<<B_ROWS / 4, 256, 0, stream>>>(feat, labels, slotOf,
                                                   G, labG, sqG);

    hipMemsetAsync(posmin, 0xFF, 65536, stream);    // posmin+negmin = +inf bits

    // 8 XCDs x 132 slots; covers worst-case 33x32 = 1056 tiles.
    tile_mindist<<<1056, 256, 0, stream>>>(G, labG, sqG, cnt, posmin, negmin);

    reduce_one<<<1, 256, 0, stream>>>(posmin, negmin, out);
}

// Round 16
// 181.551 us; speedup vs baseline: 1.3615x; 1.0075x over previous
//
#include <hip/hip_runtime.h>

// ---------------------------------------------------------------------------
// TripletContrastiveLoss on MI355X (gfx950)  — Round 16
// Base: R15 (183 µs; tile 90.6 µs; XCD strip map kept — FETCH 104->76 MB).
// ONE variable: BK=64 via SPLIT K-HALF SUB-BUFFERS. Each step stages 128 B/row
// as two 64-B-row chunks into separate 8 KB LDS arrays (k-half 0 / k-half 1),
// preserving R12's proven 64-B-row bank geometry and zero-register async
// staging. 16 steps (half the barrier/drain events), 32 MFMAs per barrier.
// R13 failed BK=64 via 128-B rows (3x conflicts); R11 via VGPR staging
// (spill). This construction avoids both. LDS 64 KB -> still 2 blocks/CU.
// ---------------------------------------------------------------------------

#define B_ROWS 8192
#define DIM    1024

typedef __bf16 bf16x8 __attribute__((ext_vector_type(8)));
typedef float  f32x4  __attribute__((ext_vector_type(4)));

__device__ __forceinline__ unsigned short f2bf_rne(float x) {
    unsigned u = __float_as_uint(x);
    unsigned r = (u + 0x7FFFu + ((u >> 16) & 1u)) >> 16;
    return (unsigned short)r;
}
__device__ __forceinline__ float bf2f(unsigned short h) {
    return __uint_as_float(((unsigned)h) << 16);
}

// Async global->LDS, 16 B per lane; LDS dest wave-uniform, lane i at base+16i.
__device__ __forceinline__ void async_copy16(const void* g, void* l) {
    __builtin_amdgcn_global_load_lds(
        (const __attribute__((address_space(1))) unsigned int*)g,
        (__attribute__((address_space(3))) unsigned int*)l,
        16, 0, 0);
}

// ---------------------------------------------------------------------------
// Kernel 0: slot assignment via LDS prefix scan. 1 block x 256 threads,
// 32 rows/thread. Zero atomics. slotOf overlays posmin (consumed by
// normalize_rows, then clobbered by the 0xFF memset — stream-ordered).
// Writes cnt[0] = nA unconditionally.
// ---------------------------------------------------------------------------
__global__ __launch_bounds__(256) void compute_slots(
    const int* __restrict__ dom, int* __restrict__ slotOf,
    unsigned* __restrict__ cnt)
{
    __shared__ int cnts[256];
    __shared__ int base[257];
    const int t = threadIdx.x;
    const int p0 = t * 32;

    unsigned mask = 0u; int c = 0;
    #pragma unroll
    for (int i = 0; i < 32; ++i) {
        const int isA = (dom[p0 + i] == 0) ? 1 : 0;
        mask |= ((unsigned)isA) << i;
        c += isA;
    }
    cnts[t] = c;
    __syncthreads();
    if (t == 0) {
        int acc = 0;
        for (int i = 0; i < 256; ++i) { base[i] = acc; acc += cnts[i]; }
        base[256] = acc;
        cnt[0] = (unsigned)acc;                  // nA
    }
    __syncthreads();
    const int nA = base[256];
    int aB = base[t];
    #pragma unroll
    for (int i = 0; i < 32; ++i) {
        const int isA = (mask >> i) & 1;
        slotOf[p0 + i] = isA ? aB : nA + (p0 + i - aB);
        aB += isA;
    }
}

// ---------------------------------------------------------------------------
// Kernel 1: one row per WAVE. 2048 blocks x 256 threads (4 waves). Wave-local
// shuffle reductions only. L2-normalize fp32, round to bf16, scatter to slot.
// sqG[slot] = sum of squares of the bf16-ROUNDED row.
// ---------------------------------------------------------------------------
__global__ __launch_bounds__(256) void normalize_rows(
    const float* __restrict__ feat, const int* __restrict__ labels,
    const int* __restrict__ slotOf, unsigned short* __restrict__ G,
    int* __restrict__ labG, float* __restrict__ sqG)
{
    const int wv = threadIdx.x >> 6, lane = threadIdx.x & 63;
    const int row = blockIdx.x * 4 + wv;

    const float4* src = (const float4*)(feat + (size_t)row * DIM);
    float4 v[4];
    float ss = 0.0f;
    #pragma unroll
    for (int j = 0; j < 4; ++j) {
        v[j] = src[j * 64 + lane];
        ss += v[j].x * v[j].x + v[j].y * v[j].y + v[j].z * v[j].z + v[j].w * v[j].w;
    }
    #pragma unroll
    for (int s = 32; s > 0; s >>= 1) ss += __shfl_xor(ss, s);
    const float inv = 1.0f / fmaxf(sqrtf(ss), 1e-12f);

    const int slot = slotOf[row];
    unsigned short ub[16];
    float ss2 = 0.0f;
    #pragma unroll
    for (int j = 0; j < 4; ++j) {
        const float f0 = v[j].x * inv, f1 = v[j].y * inv,
                    f2 = v[j].z * inv, f3 = v[j].w * inv;
        ub[j * 4 + 0] = f2bf_rne(f0); ub[j * 4 + 1] = f2bf_rne(f1);
        ub[j * 4 + 2] = f2bf_rne(f2); ub[j * 4 + 3] = f2bf_rne(f3);
        #pragma unroll
        for (int q = 0; q < 4; ++q) {
            const float fr = bf2f(ub[j * 4 + q]);
            ss2 += fr * fr;
        }
    }
    #pragma unroll
    for (int s = 32; s > 0; s >>= 1) ss2 += __shfl_xor(ss2, s);
    if (lane == 0) {
        sqG[slot]  = ss2;
        labG[slot] = labels[row];
    }
    ushort4* dst = (ushort4*)(G + (size_t)slot * DIM);
    #pragma unroll
    for (int j = 0; j < 4; ++j) {
        ushort4 pk;
        pk.x = ub[j * 4 + 0]; pk.y = ub[j * 4 + 1];
        pk.z = ub[j * 4 + 2]; pk.w = ub[j * 4 + 3];
        dst[j * 64 + lane] = pk;
    }
}

// ---------------------------------------------------------------------------
// Kernel 2: persistent 128x128 tiles, 4 waves (each 64x64 via 4x4 of
// 16x16x32 bf16 MFMA). K=1024 in 16 steps of BK=64. Each step stages two
// k-halves into SEPARATE 64-B-row sub-buffers via global_load_lds width=16
// (8 async/wave/step), double-buffered (64 KB total), ONE barrier per step.
// XCD strip map (R15): blockIdx&7 = XCD owns ceil(nTF/8) F-tile rows.
// Epilogue: min d^2 per anchor row -> atomicMin (uint order, d^2 >= 0).
// ---------------------------------------------------------------------------
__global__ __launch_bounds__(256) void tile_mindist(
    const unsigned short* __restrict__ G, const int* __restrict__ labG,
    const float* __restrict__ sqG, const unsigned* __restrict__ cnt,
    unsigned* __restrict__ posmin, unsigned* __restrict__ negmin)
{
    const int nA = (int)cnt[0];
    const int nF = B_ROWS - nA;
    const int nTA = (nA + 127) >> 7;
    const int nTF = (nF + 127) >> 7;
    if (nTA == 0 || nTF == 0) return;

    const int strip = (nTF + 7) >> 3;
    const int xcd  = blockIdx.x & 7;
    const int slot = blockIdx.x >> 3;            // 0..131
    const int tyBase = xcd * strip;
    const int nloc = nTA * strip;

    // [buf][A=0/F=1][khalf][128 rows x 32 shorts (64 B)] = 65,536 B
    __shared__ __align__(16) unsigned short S[2][2][2][128 * 32];

    const int t = threadIdx.x;
    const int lane = t & 63, w = t >> 6;
    const int wm = w >> 1, wn = w & 1;          // wave sub-tile coords (x64)
    const int l15 = lane & 15, quad = lane >> 4;

    // Async staging: chunk ch = rows [16ch,16ch+16) x 64 B; wave w owns
    // chunks 2w, 2w+1 of both arrays, both k-halves.
    const int ch0 = 2 * w;
    const int crow = lane >> 2;
    const int cbyte = (lane & 3) * 16;

    // Fragment read offsets (shorts), row stride 32 shorts.
    const int rdA = (wm * 64 + l15) * 32 + quad * 8;
    const int rdF = (wn * 64 + l15) * 32 + quad * 8;

    const char* Gb = (const char*)G;

    for (int idx = slot; idx < nloc; idx += 132) {
        const int ty = tyBase + idx / nTA;
        if (ty >= nTF) break;                    // ty monotone in idx
        const int tx = idx % nTA;
        const int rowA0 = tx * 128;
        const int rowF0 = nA + ty * 128;

        const char* ga[2]; const char* gf[2];
        #pragma unroll
        for (int h = 0; h < 2; ++h) {
            const int ch = ch0 + h;
            const int rA = rowA0 + 16 * ch + crow;          // < 8192 always
            int rF = rowF0 + 16 * ch + crow;
            if (rF > B_ROWS - 1) rF = B_ROWS - 1;           // clamp; masked later
            ga[h] = Gb + (size_t)rA * (DIM * 2) + cbyte;
            gf[h] = Gb + (size_t)rF * (DIM * 2) + cbyte;
        }

        f32x4 acc[4][4] = {};

        // Prologue: stage step 0 (both k-halves) into buffer 0.
        #pragma unroll
        for (int u = 0; u < 2; ++u)
            #pragma unroll
            for (int h = 0; h < 2; ++h) {
                async_copy16(ga[h] + u * 64, &S[0][0][u][(ch0 + h) * 512]);
                async_copy16(gf[h] + u * 64, &S[0][1][u][(ch0 + h) * 512]);
            }
        __syncthreads();                         // drains vmcnt (buf0 ready)

        #pragma unroll 2
        for (int step = 0; step < 16; ++step) {
            const int cur = step & 1;
            const int nb = cur ^ 1;
            if (step < 15) {                     // async-stage step+1 into nb
                const int off = (step + 1) * 128;  // 128 B of K per step
                #pragma unroll
                for (int u = 0; u < 2; ++u)
                    #pragma unroll
                    for (int h = 0; h < 2; ++h) {
                        async_copy16(ga[h] + off + u * 64,
                                     &S[nb][0][u][(ch0 + h) * 512]);
                        async_copy16(gf[h] + off + u * 64,
                                     &S[nb][1][u][(ch0 + h) * 512]);
                    }
            }

            #pragma unroll
            for (int u = 0; u < 2; ++u) {        // two K=32 halves
                const unsigned short* pa = &S[cur][0][u][rdA];
                const unsigned short* pf = &S[cur][1][u][rdF];
                bf16x8 a[4], b[4];
                #pragma unroll
                for (int fm = 0; fm < 4; ++fm) a[fm] = *(const bf16x8*)(pa + fm * 512);
                #pragma unroll
                for (int fn = 0; fn < 4; ++fn) b[fn] = *(const bf16x8*)(pf + fn * 512);
                #pragma unroll
                for (int fm = 0; fm < 4; ++fm)
                    #pragma unroll
                    for (int fn = 0; fn < 4; ++fn)
                        acc[fm][fn] = __builtin_amdgcn_mfma_f32_16x16x32_bf16(
                            a[fm], b[fn], acc[fm][fn], 0, 0, 0);
            }

            __syncthreads();   // one barrier: completes nb loads, frees cur
        }

        // Epilogue. C/D layout: col = lane&15 (field), row = quad*4+reg (anchor).
        const float INFV = __uint_as_float(0x7f800000u);
        float sqf[4]; int lf_[4]; bool vf[4];
        #pragma unroll
        for (int fn = 0; fn < 4; ++fn) {
            const int rf = rowF0 + wn * 64 + fn * 16 + l15;
            vf[fn] = rf < B_ROWS;
            const int rc = vf[fn] ? rf : (B_ROWS - 1);
            sqf[fn] = sqG[rc];
            lf_[fn] = labG[rc];
        }
        #pragma unroll
        for (int fm = 0; fm < 4; ++fm) {
            #pragma unroll
            for (int r = 0; r < 4; ++r) {
                const int ra = rowA0 + wm * 64 + fm * 16 + quad * 4 + r;
                const bool va = ra < nA;
                const int rac = va ? ra : 0;
                const float sqa = sqG[rac];
                const int la_ = labG[rac];
                float pmin = INFV, nmin = INFV;
                #pragma unroll
                for (int fn = 0; fn < 4; ++fn) {
                    const float dd = fmaxf(sqa + sqf[fn] - 2.0f * acc[fm][fn][r], 0.0f);
                    if (vf[fn]) {
                        if (la_ == lf_[fn]) pmin = fminf(pmin, dd);
                        else                nmin = fminf(nmin, dd);
                    }
                }
                #pragma unroll
                for (int s = 1; s < 16; s <<= 1) {
                    pmin = fminf(pmin, __shfl_xor(pmin, s));
                    nmin = fminf(nmin, __shfl_xor(nmin, s));
                }
                if (l15 == 0 && va) {
                    if (pmin < INFV) atomicMin(&posmin[ra], __float_as_uint(pmin));
                    if (nmin < INFV) atomicMin(&negmin[ra], __float_as_uint(nmin));
                }
            }
        }
        __syncthreads();   // protect LDS before next tile's prologue writes
    }
}

// ---------------------------------------------------------------------------
// Kernel 3: fused final reduce. 1 block x 256 threads, 32 independent load
// pairs per thread, wave+LDS reduce, write out[0]. Untouched slots stay
// 0xFFFFFFFF and drop out as invalid.
// ---------------------------------------------------------------------------
__global__ __launch_bounds__(256) void reduce_one(
    const unsigned* __restrict__ posmin, const unsigned* __restrict__ negmin,
    float* __restrict__ out)
{
    const int t = threadIdx.x;
    const int lane = t & 63, w = t >> 6;
    float tl = 0.0f, c = 0.0f;
    #pragma unroll
    for (int j = 0; j < 32; ++j) {
        const int i = j * 256 + t;
        const unsigned up = posmin[i], un = negmin[i];
        if (up != 0xFFFFFFFFu && un != 0xFFFFFFFFu) {
            const float pd = sqrtf(__uint_as_float(up));
            const float nd = sqrtf(__uint_as_float(un));
            tl += fmaxf(pd - nd + 0.3f, 0.0f);
            c += 1.0f;
        }
    }
    #pragma unroll
    for (int s = 32; s > 0; s >>= 1) {
        tl += __shfl_down(tl, s);
        c  += __shfl_down(c, s);
    }
    __shared__ float sb[8];
    if (lane == 0) { sb[w] = tl; sb[4 + w] = c; }
    __syncthreads();
    if (t == 0) {
        const float s = sb[0] + sb[1] + sb[2] + sb[3];
        const float cc = sb[4] + sb[5] + sb[6] + sb[7];
        out[0] = (cc > 0.0f) ? s / fmaxf(cc, 1.0f) : 0.0f;
    }
}

// ---------------------------------------------------------------------------
extern "C" void kernel_launch(void* const* d_in, const int* in_sizes, int n_in,
                              void* d_out, int out_size, void* d_ws, size_t ws_size,
                              hipStream_t stream) {
    const float* feat  = (const float*)d_in[0];
    const int* labels  = (const int*)d_in[1];
    const int* dom     = (const int*)d_in[2];
    float* out = (float*)d_out;

    char* ws = (char*)d_ws;
    // Workspace layout (bytes) — identical footprint to validated layout:
    unsigned short* G   = (unsigned short*)(ws);                 // 16,777,216
    int*      labG      = (int*)(ws + 16777216);                 //     32,768
    float*    sqG       = (float*)(ws + 16809984);               //     32,768
    unsigned* posmin    = (unsigned*)(ws + 16842752);            //     32,768
    unsigned* negmin    = (unsigned*)(ws + 16875520);            //     32,768
    unsigned* cnt       = (unsigned*)(ws + 16908288);            //  8 (nA)
    // slotOf OVERLAYS posmin: written by compute_slots, consumed by
    // normalize_rows, then clobbered by the 0xFF memset (stream-ordered).
    int*      slotOf    = (int*)(ws + 16842752);

    compute_slots<<<1, 256, 0, stream>>>(dom, slotOf, cnt);
    normalize_rows<<<B_ROWS / 4, 256, 0, stream>>>(feat, labels, slotOf,
                                                   G, labG, sqG);

    hipMemsetAsync(posmin, 0xFF, 65536, stream);    // posmin+negmin = +inf bits

    // 8 XCDs x 132 slots; covers worst-case 33x32 = 1056 tiles.
    tile_mindist<<<1056, 256, 0, stream>>>(G, labG, sqG, cnt, posmin, negmin);

    reduce_one<<<1, 256, 0, stream>>>(posmin, negmin, out);
}